// Round 14
// baseline (108.216 us; speedup 1.0000x reference)
//
#include <hip/hip_runtime.h>

#define EMBED 512
#define HEADS 8
#define HDIM 64
#define NBATCH 4
#define SEQ 2048
#define NT 32  // 64-wide kv tiles

typedef __attribute__((ext_vector_type(8))) short short8v;   // 8 bf16
typedef __attribute__((ext_vector_type(4))) float f32x4;
typedef __attribute__((ext_vector_type(16))) float f32x16;
typedef __attribute__((ext_vector_type(4))) int int4v;
typedef __attribute__((ext_vector_type(2))) unsigned u32x2;
typedef unsigned long long ull;

typedef __attribute__((address_space(1))) const void gvoid;
typedef __attribute__((address_space(3))) void lvoid;
// direct HBM/L2 -> LDS, 16B per lane; dest = wave-uniform base + lane*16
#define GLDS(gp, lp) __builtin_amdgcn_global_load_lds((gvoid*)(gp), (lvoid*)(lp), 16, 0, 0)

// raw v_exp_f32 (1 trans op); |args| << 126 here so libm guard path never needed
static __device__ __forceinline__ float exp2n(float x) {
#if __has_builtin(__builtin_amdgcn_exp2f)
  return __builtin_amdgcn_exp2f(x);
#else
  float r;
  asm("v_exp_f32 %0, %1" : "=v"(r) : "v"(x));
  return r;
#endif
}
#define EXP2(x) exp2n(x)

static __device__ __forceinline__ short f2bf(float f) {
  union { float f; unsigned u; } v; v.f = f;
  unsigned r = v.u + 0x7FFFu + ((v.u >> 16) & 1u);  // RNE
  return (short)(r >> 16);
}

static __device__ __forceinline__ int cvtpk(float a, float b) {
  int r;
  asm("v_cvt_pk_bf16_f32 %0, %1, %2" : "=v"(r) : "v"(a), "v"(b));
  return r;  // low = bf16(a), high = bf16(b)
}

// permlane32_swap: a' = {a_lo, b_lo}, b' = {a_hi, b_hi} (halves = lane<32 / >=32)
static __device__ __forceinline__ void plswap(int& a, int& b) {
#if __has_builtin(__builtin_amdgcn_permlane32_swap)
  u32x2 r = __builtin_amdgcn_permlane32_swap((unsigned)a, (unsigned)b, false, false);
  a = (int)r[0];
  b = (int)r[1];
#else
  int sa = __shfl_xor(a, 32), sb = __shfl_xor(b, 32);
  int hi = (threadIdx.x >> 5) & 1;
  int na = hi ? sb : a;
  int nb = hi ? b : sa;
  a = na;
  b = nb;
#endif
}

// 1-bit signed bitfield extract: bit -> 0x00000000 / 0xFFFFFFFF
static __device__ __forceinline__ int sbfe1(unsigned v, int off) {
#if __has_builtin(__builtin_amdgcn_sbfe)
  return __builtin_amdgcn_sbfe((int)v, off, 1);
#else
  return ((int)(v << (31 - off))) >> 31;
#endif
}

// XOR swizzle for 128-byte LDS rows: conflict-free-ish ds_read_b128 column reads.
static __device__ __forceinline__ int swz(int row, int b) {
  return row * 128 + (b ^ ((row & 7) << 4));
}

// ---------------- prep: W f32->bf16 (blocks 0..383) + mask pack (rest) -------
// pack: wave covers 256 consecutive mask elems via 4 stride-64 coalesced dword
// loads -> 4 ballots -> 4 stores. mpt layout [n][kt][q].
__global__ void __launch_bounds__(256) prep_k(const float* __restrict__ Wk,
                                              const float* __restrict__ Wv,
                                              const float* __restrict__ Wo,
                                              short* __restrict__ wbf,
                                              const int* __restrict__ mask,
                                              ull* __restrict__ mp) {
  const int bid = blockIdx.x;
  if (bid < 384) {
    int t = bid * 256 + threadIdx.x;  // 98304 threads x 8 elems
    const float* src = (t < 32768) ? Wk : ((t < 65536) ? Wv : Wo);
    int lt = t & 32767;
    const f32x4* s = (const f32x4*)src + (long)lt * 2;
    f32x4 a = s[0], b = s[1];
    int4v o = (int4v){cvtpk(a[0], a[1]), cvtpk(a[2], a[3]), cvtpk(b[0], b[1]), cvtpk(b[2], b[3])};
    *(int4v*)(wbf + (long)t * 8) = o;
  } else {
    const int pb = bid - 384;                      // 0..16383
    const int wv = threadIdx.x >> 6, lane = threadIdx.x & 63;
    const long gid0 = (long)pb * 1024 + wv * 256;  // wave's 256-elem run
    const int* m0 = mask + gid0 + lane;
    const int kt0 = ((int)(gid0 & (SEQ - 1))) >> 6;
    const long q = (gid0 >> 11) & (SEQ - 1);
    const long n = gid0 >> 22;
    const long wbase = ((n * NT) << 11) + q;
#pragma unroll
    for (int j = 0; j < 4; ++j) {
      int bit = m0[j * 64] != 0;
      ull bb = __ballot(bit);
      if (lane == 0) mp[wbase + ((long)(kt0 + j) << 11)] = bb;
    }
  }
}

// ---------------- merged K/V projection: 128x128 tile, 1 barrier/iter --------
// 1-D grid 512, XCD-chunked so the 4 n-tiles sharing one A-tile (same m,which)
// are ADJACENT within an XCD chunk -> A re-reads hit the local L2.
// which=0: kbf[n][s][e] = keys @ Wk^T ; which=1: vt[n][h][d][s] = values @ Wv^T
__global__ void __launch_bounds__(256, 2) projkv_k(const float* __restrict__ keys,
                                                   const float* __restrict__ values,
                                                   const short* __restrict__ wbf,
                                                   short* __restrict__ kbf,
                                                   short* __restrict__ vt) {
  __shared__ short As[2][8192];
  __shared__ short Bs[2][8192];
  const int bid = blockIdx.x;
  const int lid = (bid & 7) * 64 + (bid >> 3);   // 512 = 8*64, bijective
  const int n_ = lid & 3;
  const int m_ = (lid >> 2) & 63;
  const int which = lid >> 8;
  const float* A_ = which ? values : keys;
  const short* wsrc = wbf + which * 262144;
  const int m0 = m_ * 128, n0 = n_ * 128;
  const int t = threadIdx.x, lane = t & 63, wid = t >> 6;
  const int wm = wid >> 1, wn = wid & 1, lrow = lane & 15, lgrp = lane >> 4;

  const int wrow_b = wid * 32 + (lane >> 3);
  const int weo = (((lane & 7) << 4) ^ ((wrow_b & 7) << 4)) >> 1;
  const short* wgb = wsrc + (long)n0 * EMBED + weo;
  const int arow = t >> 1, ach = t & 1;
  const float* agb = A_ + (long)(m0 + arow) * EMBED + ach * 32;

#define STW(kt_, bf_) { _Pragma("unroll") for (int i = 0; i < 4; ++i) \
    GLDS(wgb + (long)(wrow_b + i * 8) * EMBED + (kt_) * 64, &Bs[bf_][(wid * 256 + i * 64) * 8]); }
#define LDA(kt_) { const f32x4* s_ = (const f32x4*)(agb + (kt_) * 64); \
    _Pragma("unroll") for (int i = 0; i < 8; ++i) areg[i] = s_[i]; }
#define WRA(bf_) { int tw[16]; \
    _Pragma("unroll") for (int i = 0; i < 8; ++i) { tw[2*i] = cvtpk(areg[i][0], areg[i][1]); tw[2*i+1] = cvtpk(areg[i][2], areg[i][3]); } \
    _Pragma("unroll") for (int c = 0; c < 4; ++c) \
      *(int4v*)((char*)As[bf_] + swz(arow, ach * 64 + c * 16)) = *(const int4v*)&tw[c * 4]; }

  f32x4 acc[4][4];
#pragma unroll
  for (int i = 0; i < 4; ++i)
#pragma unroll
    for (int j = 0; j < 4; ++j) acc[i][j] = (f32x4){0.f, 0.f, 0.f, 0.f};
  f32x4 areg[8];

  STW(0, 0); LDA(0); WRA(0);
  __syncthreads();
  for (int kt = 0; kt < 8; ++kt) {
    const int bf = kt & 1;
    if (kt < 7) { STW(kt + 1, bf ^ 1); LDA(kt + 1); }
#pragma unroll
    for (int kk = 0; kk < 2; ++kk) {
      short8v af[4], bfr[4];
#pragma unroll
      for (int mi = 0; mi < 4; ++mi)
        af[mi] = *(const short8v*)((const char*)As[bf] + swz(wm * 64 + mi * 16 + lrow, kk * 64 + lgrp * 16));
#pragma unroll
      for (int ni = 0; ni < 4; ++ni)
        bfr[ni] = *(const short8v*)((const char*)Bs[bf] + swz(wn * 64 + ni * 16 + lrow, kk * 64 + lgrp * 16));
#pragma unroll
      for (int mi = 0; mi < 4; ++mi)
#pragma unroll
        for (int ni = 0; ni < 4; ++ni)
          acc[mi][ni] = __builtin_amdgcn_mfma_f32_16x16x32_bf16(af[mi], bfr[ni], acc[mi][ni], 0, 0, 0);
    }
    if (kt < 7) WRA(bf ^ 1);
    __syncthreads();
  }
#undef STW
#undef LDA
#undef WRA

  if (which == 0) {
#pragma unroll
    for (int mi = 0; mi < 4; ++mi)
#pragma unroll
      for (int ni = 0; ni < 4; ++ni) {
        int m = m0 + wm * 64 + mi * 16 + lgrp * 4;
        int n = n0 + wn * 64 + ni * 16 + lrow;
#pragma unroll
        for (int r = 0; r < 4; ++r)
          kbf[(long)(m + r) * EMBED + n] = f2bf(acc[mi][ni][r]);
      }
  } else {
#pragma unroll
    for (int mi = 0; mi < 4; ++mi)
#pragma unroll
      for (int ni = 0; ni < 4; ++ni) {
        int m = m0 + wm * 64 + mi * 16 + lgrp * 4;   // token = n*2048 + s
        int ncol = n0 + wn * 64 + ni * 16 + lrow;
        int batch = m >> 11, s = m & (SEQ - 1);
        int hh = ncol >> 6, d = ncol & (HDIM - 1);
        short pk[4];
#pragma unroll
        for (int r = 0; r < 4; ++r) pk[r] = f2bf(acc[mi][ni][r]);
        *(ull*)&vt[((long)((batch * HEADS + hh) * HDIM + d)) * SEQ + s] = *(const ull*)pk;
      }
  }
}

// ---------------- flash attention v12: split-S + VALU lr (round-13 verbatim) -
__global__ void __launch_bounds__(512, 4) attn_k(const float* __restrict__ query,
                                                 const short* __restrict__ kbf,
                                                 const short* __restrict__ vt,
                                                 const ull* __restrict__ mpt,
                                                 short* __restrict__ oat) {
  __shared__ short KV[2][2][2][4096];  // [half][buf][K/V][64x64 bf16] = 64 KB

  const int bid = blockIdx.x;
  const int logical = ((bid & 7) << 6) | (bid >> 3);  // XCD-chunked, bijective
  const int qt = logical & 15;
  const int h = (logical >> 4) & 7;
  const int nb = logical >> 7;
  const int q0 = qt * 128;
  const int t = threadIdx.x, lane = t & 63, wid = t >> 6;
  const int qsub = wid & 3, half = wid >> 2;
  const int ql = lane & 31, hi = lane >> 5;
  const float KS = 0.0637587188f;  // log2(e)/sqrt(512), pre-applied to Q

  // ---- Q fragments direct from global (one-time gathered read) ----
  short8v qf[4];
  {
    const float* qsrc = query + (long)(nb * SEQ + q0 + qsub * 32 + ql) * EMBED + h * HDIM;
#pragma unroll
    for (int ks = 0; ks < 4; ++ks) {
      f32x4 qa = *(const f32x4*)(qsrc + ks * 16 + hi * 8);
      f32x4 qb = *(const f32x4*)(qsrc + ks * 16 + hi * 8 + 4);
      union { int4v i; short8v s; } uq;
      uq.i = (int4v){cvtpk(qa[0] * KS, qa[1] * KS), cvtpk(qa[2] * KS, qa[3] * KS),
                     cvtpk(qb[0] * KS, qb[1] * KS), cvtpk(qb[2] * KS, qb[3] * KS)};
      qf[ks] = uq.s;
    }
  }

  // ---- staging invariants (linear LDS dest, inverse-swizzled global src) ----
  const int srow = qsub * 16 + (lane >> 3);
  const int seo = (((lane & 7) << 4) ^ ((srow & 7) << 4)) >> 1;
  const short* kgb = kbf + ((long)nb * SEQ) * EMBED + h * HDIM + seo;
  const short* vgb = vt + ((long)(nb * HEADS + h) * HDIM) * SEQ + seo;
  const long koff0 = (long)srow * EMBED, koff1 = (long)(srow + 8) * EMBED;
  const long voff0 = (long)srow * SEQ,  voff1 = (long)(srow + 8) * SEQ;

#define STAGE(kt_, bf_) { \
    GLDS(kgb + (long)(kt_) * (64 * EMBED) + koff0, &KV[half][bf_][0][qsub * 1024]); \
    GLDS(kgb + (long)(kt_) * (64 * EMBED) + koff1, &KV[half][bf_][0][qsub * 1024 + 512]); \
    GLDS(vgb + (kt_) * 64 + voff0, &KV[half][bf_][1][qsub * 1024]); \
    GLDS(vgb + (kt_) * 64 + voff1, &KV[half][bf_][1][qsub * 1024 + 512]); }

  const int kt0 = half * 16;
  STAGE(kt0, 0);
  const ull* mrow = mpt + (((long)nb * NT) << 11) + q0 + qsub * 32 + ql;
  ull mw = mrow[(long)kt0 << 11];

  f32x16 ot0, ot1, zacc;
#pragma unroll
  for (int i = 0; i < 16; ++i) { ot0[i] = 0.f; ot1[i] = 0.f; zacc[i] = 0.f; }
  float lr = 0.f;  // lane-local partial denominator (cross-half fixed at merge)

  __syncthreads();  // tile 0 staged

  for (int tt = 0; tt < 16; ++tt) {
    const int bf = tt & 1;
    const int ktg = kt0 + tt;
    ull mw_next = 0;
    if (tt < 15) {
      STAGE(ktg + 1, bf ^ 1);           // in flight across this tile's compute
      mw_next = mrow[(long)(ktg + 1) << 11];
    }
    const char* Kb = (const char*)&KV[half][bf][0][0];
    const char* Vb = (const char*)&KV[half][bf][1][0];
    const ull mws = mw >> (hi << 2);
    const unsigned mword[2] = {(unsigned)mws, (unsigned)(mws >> 32)};

    // ---- two S-halves sequentially: QKT -> fused exp/mask/sum/pack/PV ----
#pragma unroll
    for (int sh = 0; sh < 2; ++sh) {
      f32x16 st;
      __builtin_amdgcn_s_setprio(1);
      {
        short8v ka = *(const short8v*)(Kb + swz(sh * 32 + ql, hi * 16));
        st = __builtin_amdgcn_mfma_f32_32x32x16_bf16(ka, qf[0], zacc, 0, 0, 0);
      }
#pragma unroll
      for (int ks = 1; ks < 4; ++ks) {
        short8v ka = *(const short8v*)(Kb + swz(sh * 32 + ql, ks * 32 + hi * 16));
        st = __builtin_amdgcn_mfma_f32_32x32x16_bf16(ka, qf[ks], st, 0, 0, 0);
      }
      __builtin_amdgcn_s_setprio(0);

#pragma unroll
      for (int ksl = 0; ksl < 2; ++ksl) {
        const int ks = sh * 2 + ksl;     // global k-slice 0..3
        const int base = ksl * 8;
        float p[8];
#pragma unroll
        for (int j = 0; j < 8; ++j) {
          const int r = base + j;
          const int cc = (r & 3) + 8 * (r >> 2);
          float e = EXP2(st[r]);
          p[j] = __int_as_float(__float_as_int(e) & sbfe1(mword[sh], cc));
        }
        lr += ((p[0] + p[1]) + (p[2] + p[3])) + ((p[4] + p[5]) + (p[6] + p[7]));
        int d0 = cvtpk(p[0], p[1]);
        int d1 = cvtpk(p[2], p[3]);
        int d2 = cvtpk(p[4], p[5]);
        int d3 = cvtpk(p[6], p[7]);
        plswap(d0, d2);  // -> w0 = {d0_lo,d2_lo}, w2 = {d0_hi,d2_hi}
        plswap(d1, d3);  // -> w1, w3
        union { int4v i; short8v s; } u;
        u.i = (int4v){d0, d1, d2, d3};
        short8v va = *(const short8v*)(Vb + swz(ql, ks * 32 + hi * 16));
        short8v vc = *(const short8v*)(Vb + swz(32 + ql, ks * 32 + hi * 16));
        __builtin_amdgcn_s_setprio(1);
        ot0 = __builtin_amdgcn_mfma_f32_32x32x16_bf16(va, u.s, ot0, 0, 0, 0);
        ot1 = __builtin_amdgcn_mfma_f32_32x32x16_bf16(vc, u.s, ot1, 0, 0, 0);
        __builtin_amdgcn_s_setprio(0);
      }
    }

    mw = mw_next;
    __syncthreads();  // next tile fully staged; all waves done with buf[bf]
  }
#undef STAGE

  // ---- merge the two kv halves (KV region is dead) ----
  float* MB = (float*)&KV[0][0][0][0];                         // 4*64*34*4 B
  short* osl = (short*)&KV[0][0][0][0] + 18432 + qsub * 2048;  // bytes 36864+
  if (half == 1) {
    float* mb = MB + ((qsub * 64) + lane) * 34;
#pragma unroll
    for (int i = 0; i < 16; ++i) { mb[i] = ot0[i]; mb[16 + i] = ot1[i]; }
    mb[32] = lr;
  }
  __syncthreads();
  if (half == 0) {
    const float* mb = MB + ((qsub * 64) + lane) * 34;
    float lpart = lr + mb[32];           // both halves, this hi-subset
    int lb = __float_as_int(lpart), lb2 = lb;
    plswap(lb, lb2);                     // cross-half: total = lo-part + hi-part
    float lsum = __int_as_float(lb) + __int_as_float(lb2);
    float linv = 1.0f / lsum;
    float oo[32];
#pragma unroll
    for (int i = 0; i < 16; ++i) {
      oo[i] = (ot0[i] + mb[i]) * linv;
      oo[16 + i] = (ot1[i] + mb[16 + i]) * linv;
    }
    // per-wave LDS transpose -> coalesced 16B stores
#pragma unroll
    for (int a = 0; a < 2; ++a)
#pragma unroll
      for (int r = 0; r < 16; r += 2) {
        int db = (r & 3) + 8 * (r >> 2) + 4 * hi + 32 * a;
        int w = cvtpk(oo[a * 16 + r], oo[a * 16 + r + 1]);
        *(int*)((char*)osl + ql * 128 + ((2 * db) ^ ((ql & 7) << 4))) = w;
      }
    int rrow = lane >> 1;
#pragma unroll
    for (int i = 0; i < 4; ++i) {
      int ci = (lane & 1) * 4 + i;
      int4v v = *(const int4v*)((const char*)osl + rrow * 128 + ((ci * 16) ^ ((rrow & 7) << 4)));
      *(int4v*)(oat + (long)(nb * SEQ + q0 + qsub * 32 + rrow) * EMBED + h * HDIM + ci * 8) = v;
    }
  }
}

// ---------------- output projection: 64x128 tile, XCD-chunked 1-D grid -------
// 4 n-tiles sharing one A-tile (same m) adjacent within an XCD chunk.
__global__ void __launch_bounds__(256, 2) outproj_k(const short* __restrict__ oatp,
                                                    const short* __restrict__ wbf,
                                                    const float* __restrict__ bias,
                                                    float* __restrict__ out) {
  __shared__ short As[2][4096];
  __shared__ short Bs[2][8192];
  const short* wsrc = wbf + 524288;
  const int bid = blockIdx.x;
  const int lid = (bid & 7) * 64 + (bid >> 3);   // 512 = 8*64, bijective
  const int n_ = lid & 3;
  const int m_ = lid >> 2;                       // 0..127
  const int m0 = m_ * 64, n0 = n_ * 128;
  const int t = threadIdx.x, lane = t & 63, wid = t >> 6;
  const int wm = wid >> 1, wn = wid & 1, lrow = lane & 15, lgrp = lane >> 4;

  const int wrow_b = wid * 32 + (lane >> 3);
  const int weo = (((lane & 7) << 4) ^ ((wrow_b & 7) << 4)) >> 1;
  const short* wgb = wsrc + (long)n0 * EMBED + weo;
  const int arow_b = wid * 16 + (lane >> 3);
  const int aeo = (((lane & 7) << 4) ^ ((arow_b & 7) << 4)) >> 1;
  const short* agb = oatp + (long)m0 * EMBED + aeo;

#define STW2(kt_, bf_) { _Pragma("unroll") for (int i = 0; i < 4; ++i) \
    GLDS(wgb + (long)(wrow_b + i * 8) * EMBED + (kt_) * 64, &Bs[bf_][(wid * 256 + i * 64) * 8]); }
#define STA2(kt_, bf_) { _Pragma("unroll") for (int i = 0; i < 2; ++i) \
    GLDS(agb + (long)(arow_b + i * 8) * EMBED + (kt_) * 64, &As[bf_][(wid * 128 + i * 64) * 8]); }

  f32x4 acc[2][4];
#pragma unroll
  for (int i = 0; i < 2; ++i)
#pragma unroll
    for (int j = 0; j < 4; ++j) acc[i][j] = (f32x4){0.f, 0.f, 0.f, 0.f};

  STW2(0, 0); STA2(0, 0);
  __syncthreads();
  for (int kt = 0; kt < 8; ++kt) {
    const int bf = kt & 1;
    if (kt < 7) { STW2(kt + 1, bf ^ 1); STA2(kt + 1, bf ^ 1); }
#pragma unroll
    for (int kk = 0; kk < 2; ++kk) {
      short8v af[2], bfr[4];
#pragma unroll
      for (int mi = 0; mi < 2; ++mi)
        af[mi] = *(const short8v*)((const char*)As[bf] + swz(wm * 32 + mi * 16 + lrow, kk * 64 + lgrp * 16));
#pragma unroll
      for (int ni = 0; ni < 4; ++ni)
        bfr[ni] = *(const short8v*)((const char*)Bs[bf] + swz(wn * 64 + ni * 16 + lrow, kk * 64 + lgrp * 16));
#pragma unroll
      for (int mi = 0; mi < 2; ++mi)
#pragma unroll
        for (int ni = 0; ni < 4; ++ni)
          acc[mi][ni] = __builtin_amdgcn_mfma_f32_16x16x32_bf16(af[mi], bfr[ni], acc[mi][ni], 0, 0, 0);
    }
    __syncthreads();
  }
#undef STW2
#undef STA2

#pragma unroll
  for (int mi = 0; mi < 2; ++mi)
#pragma unroll
    for (int ni = 0; ni < 4; ++ni) {
      int m = m0 + wm * 32 + mi * 16 + lgrp * 4;
      int n = n0 + wn * 64 + ni * 16 + lrow;
      float b = bias[n];
#pragma unroll
      for (int r = 0; r < 4; ++r)
        out[(long)(m + r) * EMBED + n] = acc[mi][ni][r] + b;
    }
}

extern "C" void kernel_launch(void* const* d_in, const int* in_sizes, int n_in,
                              void* d_out, int out_size, void* d_ws, size_t ws_size,
                              hipStream_t stream) {
  const float* values = (const float*)d_in[0];
  const float* keys   = (const float*)d_in[1];
  const float* query  = (const float*)d_in[2];
  const int*   mask   = (const int*)d_in[3];
  // d_in[4] = Wq: computed-then-discarded in the reference (bug-faithful skip)
  const float* Wk = (const float*)d_in[5];
  const float* Wv = (const float*)d_in[6];
  const float* Wo = (const float*)d_in[7];
  const float* bo = (const float*)d_in[8];
  float* out = (float*)d_out;

  char* ws = (char*)d_ws;
  short* kbf = (short*)ws;                              // 8 MB [N][S][E] bf16
  short* vt  = (short*)(ws + (8u << 20));               // 8 MB [N][H][D][S] bf16
  short* oat = (short*)(ws + (16u << 20));              // 8 MB [N][S][E] bf16
  ull*   mpt = (ull*)(ws + (24u << 20));                // 2 MB [N][NT][S]
  short* wbf = (short*)(ws + (26u << 20));              // 1.5 MB Wk|Wv|Wo bf16

  prep_k<<<384 + 16384, 256, 0, stream>>>(Wk, Wv, Wo, wbf, mask, mpt);
  projkv_k<<<512, 256, 0, stream>>>(keys, values, wbf, kbf, vt);
  attn_k<<<512, 512, 0, stream>>>(query, kbf, vt, mpt, oat);
  outproj_k<<<512, 256, 0, stream>>>(oat, wbf, bo, out);
}

// Round 15
// 106.639 us; speedup vs baseline: 1.0148x; 1.0148x over previous
//
#include <hip/hip_runtime.h>

#define EMBED 512
#define HEADS 8
#define HDIM 64
#define NBATCH 4
#define SEQ 2048
#define NT 32  // 64-wide kv tiles

typedef __attribute__((ext_vector_type(8))) short short8v;   // 8 bf16
typedef __attribute__((ext_vector_type(4))) float f32x4;
typedef __attribute__((ext_vector_type(16))) float f32x16;
typedef __attribute__((ext_vector_type(4))) int int4v;
typedef __attribute__((ext_vector_type(2))) unsigned u32x2;
typedef unsigned long long ull;

typedef __attribute__((address_space(1))) const void gvoid;
typedef __attribute__((address_space(3))) void lvoid;
// direct HBM/L2 -> LDS, 16B per lane; dest = wave-uniform base + lane*16
#define GLDS(gp, lp) __builtin_amdgcn_global_load_lds((gvoid*)(gp), (lvoid*)(lp), 16, 0, 0)

// raw v_exp_f32 (1 trans op); |args| << 126 here so libm guard path never needed
static __device__ __forceinline__ float exp2n(float x) {
#if __has_builtin(__builtin_amdgcn_exp2f)
  return __builtin_amdgcn_exp2f(x);
#else
  float r;
  asm("v_exp_f32 %0, %1" : "=v"(r) : "v"(x));
  return r;
#endif
}
#define EXP2(x) exp2n(x)

static __device__ __forceinline__ short f2bf(float f) {
  union { float f; unsigned u; } v; v.f = f;
  unsigned r = v.u + 0x7FFFu + ((v.u >> 16) & 1u);  // RNE
  return (short)(r >> 16);
}

static __device__ __forceinline__ int cvtpk(float a, float b) {
  int r;
  asm("v_cvt_pk_bf16_f32 %0, %1, %2" : "=v"(r) : "v"(a), "v"(b));
  return r;  // low = bf16(a), high = bf16(b)
}

// permlane32_swap: a' = {a_lo, b_lo}, b' = {a_hi, b_hi} (halves = lane<32 / >=32)
static __device__ __forceinline__ void plswap(int& a, int& b) {
#if __has_builtin(__builtin_amdgcn_permlane32_swap)
  u32x2 r = __builtin_amdgcn_permlane32_swap((unsigned)a, (unsigned)b, false, false);
  a = (int)r[0];
  b = (int)r[1];
#else
  int sa = __shfl_xor(a, 32), sb = __shfl_xor(b, 32);
  int hi = (threadIdx.x >> 5) & 1;
  int na = hi ? sb : a;
  int nb = hi ? b : sa;
  a = na;
  b = nb;
#endif
}

// 1-bit signed bitfield extract: bit -> 0x00000000 / 0xFFFFFFFF
static __device__ __forceinline__ int sbfe1(unsigned v, int off) {
#if __has_builtin(__builtin_amdgcn_sbfe)
  return __builtin_amdgcn_sbfe((int)v, off, 1);
#else
  return ((int)(v << (31 - off))) >> 31;
#endif
}

// XOR swizzle for 128-byte LDS rows: conflict-free-ish ds_read_b128 column reads.
static __device__ __forceinline__ int swz(int row, int b) {
  return row * 128 + (b ^ ((row & 7) << 4));
}

// ---------------- prep: W f32->bf16 (blocks 0..383) + mask pack (rest) -------
// pack: wave covers 256 consecutive mask elems via 4 stride-64 coalesced dword
// loads -> 4 ballots -> 4 stores. mpt layout [n][kt][q].
__global__ void __launch_bounds__(256) prep_k(const float* __restrict__ Wk,
                                              const float* __restrict__ Wv,
                                              const float* __restrict__ Wo,
                                              short* __restrict__ wbf,
                                              const int* __restrict__ mask,
                                              ull* __restrict__ mp) {
  const int bid = blockIdx.x;
  if (bid < 384) {
    int t = bid * 256 + threadIdx.x;  // 98304 threads x 8 elems
    const float* src = (t < 32768) ? Wk : ((t < 65536) ? Wv : Wo);
    int lt = t & 32767;
    const f32x4* s = (const f32x4*)src + (long)lt * 2;
    f32x4 a = s[0], b = s[1];
    int4v o = (int4v){cvtpk(a[0], a[1]), cvtpk(a[2], a[3]), cvtpk(b[0], b[1]), cvtpk(b[2], b[3])};
    *(int4v*)(wbf + (long)t * 8) = o;
  } else {
    const int pb = bid - 384;                      // 0..16383
    const int wv = threadIdx.x >> 6, lane = threadIdx.x & 63;
    const long gid0 = (long)pb * 1024 + wv * 256;  // wave's 256-elem run
    const int* m0 = mask + gid0 + lane;
    const int kt0 = ((int)(gid0 & (SEQ - 1))) >> 6;
    const long q = (gid0 >> 11) & (SEQ - 1);
    const long n = gid0 >> 22;
    const long wbase = ((n * NT) << 11) + q;
#pragma unroll
    for (int j = 0; j < 4; ++j) {
      int bit = m0[j * 64] != 0;
      ull bb = __ballot(bit);
      if (lane == 0) mp[wbase + ((long)(kt0 + j) << 11)] = bb;
    }
  }
}

// ---------------- merged K/V projection: 128x128 tile, 1 barrier/iter --------
// z=0: kbf[n][s][e] = keys @ Wk^T ; z=1: vt[n][h][d][s] = values @ Wv^T
__global__ void __launch_bounds__(256, 2) projkv_k(const float* __restrict__ keys,
                                                   const float* __restrict__ values,
                                                   const short* __restrict__ wbf,
                                                   short* __restrict__ kbf,
                                                   short* __restrict__ vt) {
  __shared__ short As[2][8192];
  __shared__ short Bs[2][8192];
  const int which = blockIdx.z;
  const float* A_ = which ? values : keys;
  const short* wsrc = wbf + which * 262144;
  const int m0 = blockIdx.x * 128, n0 = blockIdx.y * 128;
  const int t = threadIdx.x, lane = t & 63, wid = t >> 6;
  const int wm = wid >> 1, wn = wid & 1, lrow = lane & 15, lgrp = lane >> 4;

  const int wrow_b = wid * 32 + (lane >> 3);
  const int weo = (((lane & 7) << 4) ^ ((wrow_b & 7) << 4)) >> 1;
  const short* wgb = wsrc + (long)n0 * EMBED + weo;
  const int arow = t >> 1, ach = t & 1;
  const float* agb = A_ + (long)(m0 + arow) * EMBED + ach * 32;

#define STW(kt_, bf_) { _Pragma("unroll") for (int i = 0; i < 4; ++i) \
    GLDS(wgb + (long)(wrow_b + i * 8) * EMBED + (kt_) * 64, &Bs[bf_][(wid * 256 + i * 64) * 8]); }
#define LDA(kt_) { const f32x4* s_ = (const f32x4*)(agb + (kt_) * 64); \
    _Pragma("unroll") for (int i = 0; i < 8; ++i) areg[i] = s_[i]; }
#define WRA(bf_) { int tw[16]; \
    _Pragma("unroll") for (int i = 0; i < 8; ++i) { tw[2*i] = cvtpk(areg[i][0], areg[i][1]); tw[2*i+1] = cvtpk(areg[i][2], areg[i][3]); } \
    _Pragma("unroll") for (int c = 0; c < 4; ++c) \
      *(int4v*)((char*)As[bf_] + swz(arow, ach * 64 + c * 16)) = *(const int4v*)&tw[c * 4]; }

  f32x4 acc[4][4];
#pragma unroll
  for (int i = 0; i < 4; ++i)
#pragma unroll
    for (int j = 0; j < 4; ++j) acc[i][j] = (f32x4){0.f, 0.f, 0.f, 0.f};
  f32x4 areg[8];

  STW(0, 0); LDA(0); WRA(0);
  __syncthreads();
  for (int kt = 0; kt < 8; ++kt) {
    const int bf = kt & 1;
    if (kt < 7) { STW(kt + 1, bf ^ 1); LDA(kt + 1); }
#pragma unroll
    for (int kk = 0; kk < 2; ++kk) {
      short8v af[4], bfr[4];
#pragma unroll
      for (int mi = 0; mi < 4; ++mi)
        af[mi] = *(const short8v*)((const char*)As[bf] + swz(wm * 64 + mi * 16 + lrow, kk * 64 + lgrp * 16));
#pragma unroll
      for (int ni = 0; ni < 4; ++ni)
        bfr[ni] = *(const short8v*)((const char*)Bs[bf] + swz(wn * 64 + ni * 16 + lrow, kk * 64 + lgrp * 16));
#pragma unroll
      for (int mi = 0; mi < 4; ++mi)
#pragma unroll
        for (int ni = 0; ni < 4; ++ni)
          acc[mi][ni] = __builtin_amdgcn_mfma_f32_16x16x32_bf16(af[mi], bfr[ni], acc[mi][ni], 0, 0, 0);
    }
    if (kt < 7) WRA(bf ^ 1);
    __syncthreads();
  }
#undef STW
#undef LDA
#undef WRA

  if (which == 0) {
#pragma unroll
    for (int mi = 0; mi < 4; ++mi)
#pragma unroll
      for (int ni = 0; ni < 4; ++ni) {
        int m = m0 + wm * 64 + mi * 16 + lgrp * 4;
        int n = n0 + wn * 64 + ni * 16 + lrow;
#pragma unroll
        for (int r = 0; r < 4; ++r)
          kbf[(long)(m + r) * EMBED + n] = f2bf(acc[mi][ni][r]);
      }
  } else {
#pragma unroll
    for (int mi = 0; mi < 4; ++mi)
#pragma unroll
      for (int ni = 0; ni < 4; ++ni) {
        int m = m0 + wm * 64 + mi * 16 + lgrp * 4;   // token = n*2048 + s
        int ncol = n0 + wn * 64 + ni * 16 + lrow;
        int batch = m >> 11, s = m & (SEQ - 1);
        int hh = ncol >> 6, d = ncol & (HDIM - 1);
        short pk[4];
#pragma unroll
        for (int r = 0; r < 4; ++r) pk[r] = f2bf(acc[mi][ni][r]);
        *(ull*)&vt[((long)((batch * HEADS + hh) * HDIM + d)) * SEQ + s] = *(const ull*)pk;
      }
  }
}

// ---------------- flash attention v12: split-S + VALU lr (best: 106.6us) -----
// Block = 8 waves (512 thr): 4 q-subtiles x 2 kv-halves over 128 q rows.
__global__ void __launch_bounds__(512, 4) attn_k(const float* __restrict__ query,
                                                 const short* __restrict__ kbf,
                                                 const short* __restrict__ vt,
                                                 const ull* __restrict__ mpt,
                                                 short* __restrict__ oat) {
  __shared__ short KV[2][2][2][4096];  // [half][buf][K/V][64x64 bf16] = 64 KB

  const int bid = blockIdx.x;
  const int logical = ((bid & 7) << 6) | (bid >> 3);  // XCD-chunked, bijective
  const int qt = logical & 15;
  const int h = (logical >> 4) & 7;
  const int nb = logical >> 7;
  const int q0 = qt * 128;
  const int t = threadIdx.x, lane = t & 63, wid = t >> 6;
  const int qsub = wid & 3, half = wid >> 2;
  const int ql = lane & 31, hi = lane >> 5;
  const float KS = 0.0637587188f;  // log2(e)/sqrt(512), pre-applied to Q

  // ---- Q fragments direct from global (one-time gathered read) ----
  short8v qf[4];
  {
    const float* qsrc = query + (long)(nb * SEQ + q0 + qsub * 32 + ql) * EMBED + h * HDIM;
#pragma unroll
    for (int ks = 0; ks < 4; ++ks) {
      f32x4 qa = *(const f32x4*)(qsrc + ks * 16 + hi * 8);
      f32x4 qb = *(const f32x4*)(qsrc + ks * 16 + hi * 8 + 4);
      union { int4v i; short8v s; } uq;
      uq.i = (int4v){cvtpk(qa[0] * KS, qa[1] * KS), cvtpk(qa[2] * KS, qa[3] * KS),
                     cvtpk(qb[0] * KS, qb[1] * KS), cvtpk(qb[2] * KS, qb[3] * KS)};
      qf[ks] = uq.s;
    }
  }

  // ---- staging invariants (linear LDS dest, inverse-swizzled global src) ----
  const int srow = qsub * 16 + (lane >> 3);
  const int seo = (((lane & 7) << 4) ^ ((srow & 7) << 4)) >> 1;
  const short* kgb = kbf + ((long)nb * SEQ) * EMBED + h * HDIM + seo;
  const short* vgb = vt + ((long)(nb * HEADS + h) * HDIM) * SEQ + seo;
  const long koff0 = (long)srow * EMBED, koff1 = (long)(srow + 8) * EMBED;
  const long voff0 = (long)srow * SEQ,  voff1 = (long)(srow + 8) * SEQ;

#define STAGE(kt_, bf_) { \
    GLDS(kgb + (long)(kt_) * (64 * EMBED) + koff0, &KV[half][bf_][0][qsub * 1024]); \
    GLDS(kgb + (long)(kt_) * (64 * EMBED) + koff1, &KV[half][bf_][0][qsub * 1024 + 512]); \
    GLDS(vgb + (kt_) * 64 + voff0, &KV[half][bf_][1][qsub * 1024]); \
    GLDS(vgb + (kt_) * 64 + voff1, &KV[half][bf_][1][qsub * 1024 + 512]); }

  const int kt0 = half * 16;
  STAGE(kt0, 0);
  const ull* mrow = mpt + (((long)nb * NT) << 11) + q0 + qsub * 32 + ql;
  ull mw = mrow[(long)kt0 << 11];

  f32x16 ot0, ot1, zacc;
#pragma unroll
  for (int i = 0; i < 16; ++i) { ot0[i] = 0.f; ot1[i] = 0.f; zacc[i] = 0.f; }
  float lr = 0.f;  // lane-local partial denominator (cross-half fixed at merge)

  __syncthreads();  // tile 0 staged

  for (int tt = 0; tt < 16; ++tt) {
    const int bf = tt & 1;
    const int ktg = kt0 + tt;
    ull mw_next = 0;
    if (tt < 15) {
      STAGE(ktg + 1, bf ^ 1);           // in flight across this tile's compute
      mw_next = mrow[(long)(ktg + 1) << 11];
    }
    const char* Kb = (const char*)&KV[half][bf][0][0];
    const char* Vb = (const char*)&KV[half][bf][1][0];
    const ull mws = mw >> (hi << 2);
    const unsigned mword[2] = {(unsigned)mws, (unsigned)(mws >> 32)};

    // ---- two S-halves sequentially: QKT -> fused exp/mask/sum/pack/PV ----
#pragma unroll
    for (int sh = 0; sh < 2; ++sh) {
      f32x16 st;
      __builtin_amdgcn_s_setprio(1);
      {
        short8v ka = *(const short8v*)(Kb + swz(sh * 32 + ql, hi * 16));
        st = __builtin_amdgcn_mfma_f32_32x32x16_bf16(ka, qf[0], zacc, 0, 0, 0);
      }
#pragma unroll
      for (int ks = 1; ks < 4; ++ks) {
        short8v ka = *(const short8v*)(Kb + swz(sh * 32 + ql, ks * 32 + hi * 16));
        st = __builtin_amdgcn_mfma_f32_32x32x16_bf16(ka, qf[ks], st, 0, 0, 0);
      }
      __builtin_amdgcn_s_setprio(0);

#pragma unroll
      for (int ksl = 0; ksl < 2; ++ksl) {
        const int ks = sh * 2 + ksl;     // global k-slice 0..3
        const int base = ksl * 8;
        float p[8];
#pragma unroll
        for (int j = 0; j < 8; ++j) {
          const int r = base + j;
          const int cc = (r & 3) + 8 * (r >> 2);
          float e = EXP2(st[r]);
          p[j] = __int_as_float(__float_as_int(e) & sbfe1(mword[sh], cc));
        }
        lr += ((p[0] + p[1]) + (p[2] + p[3])) + ((p[4] + p[5]) + (p[6] + p[7]));
        int d0 = cvtpk(p[0], p[1]);
        int d1 = cvtpk(p[2], p[3]);
        int d2 = cvtpk(p[4], p[5]);
        int d3 = cvtpk(p[6], p[7]);
        plswap(d0, d2);  // -> w0 = {d0_lo,d2_lo}, w2 = {d0_hi,d2_hi}
        plswap(d1, d3);  // -> w1, w3
        union { int4v i; short8v s; } u;
        u.i = (int4v){d0, d1, d2, d3};
        short8v va = *(const short8v*)(Vb + swz(ql, ks * 32 + hi * 16));
        short8v vc = *(const short8v*)(Vb + swz(32 + ql, ks * 32 + hi * 16));
        __builtin_amdgcn_s_setprio(1);
        ot0 = __builtin_amdgcn_mfma_f32_32x32x16_bf16(va, u.s, ot0, 0, 0, 0);
        ot1 = __builtin_amdgcn_mfma_f32_32x32x16_bf16(vc, u.s, ot1, 0, 0, 0);
        __builtin_amdgcn_s_setprio(0);
      }
    }

    mw = mw_next;
    __syncthreads();  // next tile fully staged; all waves done with buf[bf]
  }
#undef STAGE

  // ---- merge the two kv halves (KV region is dead) ----
  float* MB = (float*)&KV[0][0][0][0];                         // 4*64*34*4 B
  short* osl = (short*)&KV[0][0][0][0] + 18432 + qsub * 2048;  // bytes 36864+
  if (half == 1) {
    float* mb = MB + ((qsub * 64) + lane) * 34;
#pragma unroll
    for (int i = 0; i < 16; ++i) { mb[i] = ot0[i]; mb[16 + i] = ot1[i]; }
    mb[32] = lr;
  }
  __syncthreads();
  if (half == 0) {
    const float* mb = MB + ((qsub * 64) + lane) * 34;
    float lpart = lr + mb[32];           // both halves, this hi-subset
    int lb = __float_as_int(lpart), lb2 = lb;
    plswap(lb, lb2);                     // cross-half: total = lo-part + hi-part
    float lsum = __int_as_float(lb) + __int_as_float(lb2);
    float linv = 1.0f / lsum;
    float oo[32];
#pragma unroll
    for (int i = 0; i < 16; ++i) {
      oo[i] = (ot0[i] + mb[i]) * linv;
      oo[16 + i] = (ot1[i] + mb[16 + i]) * linv;
    }
    // per-wave LDS transpose -> coalesced 16B stores
#pragma unroll
    for (int a = 0; a < 2; ++a)
#pragma unroll
      for (int r = 0; r < 16; r += 2) {
        int db = (r & 3) + 8 * (r >> 2) + 4 * hi + 32 * a;
        int w = cvtpk(oo[a * 16 + r], oo[a * 16 + r + 1]);
        *(int*)((char*)osl + ql * 128 + ((2 * db) ^ ((ql & 7) << 4))) = w;
      }
    int rrow = lane >> 1;
#pragma unroll
    for (int i = 0; i < 4; ++i) {
      int ci = (lane & 1) * 4 + i;
      int4v v = *(const int4v*)((const char*)osl + rrow * 128 + ((ci * 16) ^ ((rrow & 7) << 4)));
      *(int4v*)(oat + (long)(nb * SEQ + q0 + qsub * 32 + rrow) * EMBED + h * HDIM + ci * 8) = v;
    }
  }
}

// ---------------- output projection: 64x128 tile, all-bf16 GLDS staging ------
__global__ void __launch_bounds__(256, 2) outproj_k(const short* __restrict__ oatp,
                                                    const short* __restrict__ wbf,
                                                    const float* __restrict__ bias,
                                                    float* __restrict__ out) {
  __shared__ short As[2][4096];
  __shared__ short Bs[2][8192];
  const short* wsrc = wbf + 524288;
  const int m0 = blockIdx.x * 64, n0 = blockIdx.y * 128;
  const int t = threadIdx.x, lane = t & 63, wid = t >> 6;
  const int wm = wid >> 1, wn = wid & 1, lrow = lane & 15, lgrp = lane >> 4;

  const int wrow_b = wid * 32 + (lane >> 3);
  const int weo = (((lane & 7) << 4) ^ ((wrow_b & 7) << 4)) >> 1;
  const short* wgb = wsrc + (long)n0 * EMBED + weo;
  const int arow_b = wid * 16 + (lane >> 3);
  const int aeo = (((lane & 7) << 4) ^ ((arow_b & 7) << 4)) >> 1;
  const short* agb = oatp + (long)m0 * EMBED + aeo;

#define STW2(kt_, bf_) { _Pragma("unroll") for (int i = 0; i < 4; ++i) \
    GLDS(wgb + (long)(wrow_b + i * 8) * EMBED + (kt_) * 64, &Bs[bf_][(wid * 256 + i * 64) * 8]); }
#define STA2(kt_, bf_) { _Pragma("unroll") for (int i = 0; i < 2; ++i) \
    GLDS(agb + (long)(arow_b + i * 8) * EMBED + (kt_) * 64, &As[bf_][(wid * 128 + i * 64) * 8]); }

  f32x4 acc[2][4];
#pragma unroll
  for (int i = 0; i < 2; ++i)
#pragma unroll
    for (int j = 0; j < 4; ++j) acc[i][j] = (f32x4){0.f, 0.f, 0.f, 0.f};

  STW2(0, 0); STA2(0, 0);
  __syncthreads();
  for (int kt = 0; kt < 8; ++kt) {
    const int bf = kt & 1;
    if (kt < 7) { STW2(kt + 1, bf ^ 1); STA2(kt + 1, bf ^ 1); }
#pragma unroll
    for (int kk = 0; kk < 2; ++kk) {
      short8v af[2], bfr[4];
#pragma unroll
      for (int mi = 0; mi < 2; ++mi)
        af[mi] = *(const short8v*)((const char*)As[bf] + swz(wm * 32 + mi * 16 + lrow, kk * 64 + lgrp * 16));
#pragma unroll
      for (int ni = 0; ni < 4; ++ni)
        bfr[ni] = *(const short8v*)((const char*)Bs[bf] + swz(wn * 64 + ni * 16 + lrow, kk * 64 + lgrp * 16));
#pragma unroll
      for (int mi = 0; mi < 2; ++mi)
#pragma unroll
        for (int ni = 0; ni < 4; ++ni)
          acc[mi][ni] = __builtin_amdgcn_mfma_f32_16x16x32_bf16(af[mi], bfr[ni], acc[mi][ni], 0, 0, 0);
    }
    __syncthreads();
  }
#undef STW2
#undef STA2

#pragma unroll
  for (int mi = 0; mi < 2; ++mi)
#pragma unroll
    for (int ni = 0; ni < 4; ++ni) {
      int m = m0 + wm * 32 + mi * 16 + lgrp * 4;
      int n = n0 + wn * 64 + ni * 16 + lrow;
      float b = bias[n];
#pragma unroll
      for (int r = 0; r < 4; ++r)
        out[(long)(m + r) * EMBED + n] = acc[mi][ni][r] + b;
    }
}

extern "C" void kernel_launch(void* const* d_in, const int* in_sizes, int n_in,
                              void* d_out, int out_size, void* d_ws, size_t ws_size,
                              hipStream_t stream) {
  const float* values = (const float*)d_in[0];
  const float* keys   = (const float*)d_in[1];
  const float* query  = (const float*)d_in[2];
  const int*   mask   = (const int*)d_in[3];
  // d_in[4] = Wq: computed-then-discarded in the reference (bug-faithful skip)
  const float* Wk = (const float*)d_in[5];
  const float* Wv = (const float*)d_in[6];
  const float* Wo = (const float*)d_in[7];
  const float* bo = (const float*)d_in[8];
  float* out = (float*)d_out;

  char* ws = (char*)d_ws;
  short* kbf = (short*)ws;                              // 8 MB [N][S][E] bf16
  short* vt  = (short*)(ws + (8u << 20));               // 8 MB [N][H][D][S] bf16
  short* oat = (short*)(ws + (16u << 20));              // 8 MB [N][S][E] bf16
  ull*   mpt = (ull*)(ws + (24u << 20));                // 2 MB [N][NT][S]
  short* wbf = (short*)(ws + (26u << 20));              // 1.5 MB Wk|Wv|Wo bf16

  prep_k<<<384 + 16384, 256, 0, stream>>>(Wk, Wv, Wo, wbf, mask, mpt);
  projkv_k<<<dim3(64, 4, 2), 256, 0, stream>>>(keys, values, wbf, kbf, vt);
  attn_k<<<512, 512, 0, stream>>>(query, kbf, vt, mpt, oat);
  outproj_k<<<dim3(128, 4), 256, 0, stream>>>(oat, wbf, bo, out);
}